// Round 2
// baseline (165.603 us; speedup 1.0000x reference)
//
#include <hip/hip_runtime.h>

#define L 512               // lattice side
#define LM (L - 1)          // 511 mask
#define VROW (L / 4)        // 128 vec4 per row
#define VROW_SHIFT 7
#define RSTRIP 16           // rows per thread (register rolling)

__global__ __launch_bounds__(256) void stencil5_roll_kernel(
    const float4* __restrict__ x4,
    const float*  __restrict__ x,
    float4* __restrict__ out4,
    const float* __restrict__ dp,
    const float* __restrict__ v1p,
    const float* __restrict__ v2p,
    const float* __restrict__ bfp)
{
    const float d  = *dp;
    const float v1 = *v1p;
    const float v2 = *v2p;
    const float bf = *bfp;
    const float D  = d * d;
    const float k_c = 1.0f - 4.0f * D;   // diagonal
    const float k_r = D - 0.5f * v1;     // x[col+1]
    const float k_l = D + 0.5f * v1;     // x[col-1]
    const float k_u = D - 0.5f * v2;     // x[row-1]
    const float k_d = D + 0.5f * v2;     // x[row+1]

    // thread -> (sample, row-strip, vcol); consecutive threads = consecutive vcol
    const int tid    = blockIdx.x * blockDim.x + threadIdx.x;
    const int vcol   = tid & (VROW - 1);
    const int strip  = tid >> VROW_SHIFT;
    const int rstrip = strip & (L / RSTRIP - 1);   // 32 strips/sample
    const int sample = strip >> 5;                 // log2(512/16)=5
    const int base_v = sample << 16;               // sample * 65536 vec4s
    const int r0     = rstrip << 4;                // * RSTRIP

    // rolling registers: up = row r-1, ctr = row r
    float4 up  = x4[base_v + (((r0 - 1) & LM) << VROW_SHIFT) + vcol];
    float4 ctr = x4[base_v + (r0 << VROW_SHIFT) + vcol];

    const int c       = vcol << 2;
    const int le_col  = (c - 1) & LM;
    const int re_col  = (c + 4) & LM;

    #pragma unroll
    for (int i = 0; i < RSTRIP; ++i) {
        const int r      = r0 + i;
        const int row_v  = base_v + (r << VROW_SHIFT);
        const float4 dn  = x4[base_v + (((r + 1) & LM) << VROW_SHIFT) + vcol];

        const size_t rowbase_e = ((size_t)row_v) << 2;
        const float  le = x[rowbase_e + (size_t)le_col];   // L1-hit: neighbor's ctr line
        const float  re = x[rowbase_e + (size_t)re_col];

        float4 o;
        o.x = k_c * ctr.x + k_r * ctr.y + k_l * le    + k_u * up.x + k_d * dn.x + bf;
        o.y = k_c * ctr.y + k_r * ctr.z + k_l * ctr.x + k_u * up.y + k_d * dn.y + bf;
        o.z = k_c * ctr.z + k_r * ctr.w + k_l * ctr.y + k_u * up.z + k_d * dn.z + bf;
        o.w = k_c * ctr.w + k_r * re    + k_l * ctr.z + k_u * up.w + k_d * dn.w + bf;
        out4[row_v + vcol] = o;

        up  = ctr;          // roll
        ctr = dn;
    }
}

extern "C" void kernel_launch(void* const* d_in, const int* in_sizes, int n_in,
                              void* d_out, int out_size, void* d_ws, size_t ws_size,
                              hipStream_t stream) {
    const float* x   = (const float*)d_in[0];
    const float* dp  = (const float*)d_in[1];
    const float* v1p = (const float*)d_in[2];
    const float* v2p = (const float*)d_in[3];
    const float* bfp = (const float*)d_in[4];
    float* out = (float*)d_out;

    const int total_vec = in_sizes[0] / 4;          // 16,777,216 vec4s
    const int threads   = total_vec / RSTRIP;       // 1,048,576 threads
    const int block     = 256;
    const int grid      = threads / block;          // 4096 blocks, exact cover

    stencil5_roll_kernel<<<grid, block, 0, stream>>>(
        (const float4*)x, x, (float4*)out, dp, v1p, v2p, bfp);
}

// Round 3
// 102.971 us; speedup vs baseline: 1.6082x; 1.6082x over previous
//
#include <hip/hip_runtime.h>

#define L 512               // lattice side
#define LM (L - 1)          // 511 mask
#define VROW (L / 4)        // 128 vec4 per row
#define VROW_SHIFT 7
#define NXCD 8

__global__ __launch_bounds__(256) void stencil5_swz_kernel(
    const float4* __restrict__ x4,
    const float*  __restrict__ x,
    float4* __restrict__ out4,
    const float* __restrict__ dp,
    const float* __restrict__ v1p,
    const float* __restrict__ v2p,
    const float* __restrict__ bfp,
    int blocks_per_xcd)
{
    const float d  = *dp;
    const float v1 = *v1p;
    const float v2 = *v2p;
    const float bf = *bfp;
    const float D  = d * d;
    const float k_c = 1.0f - 4.0f * D;   // diagonal
    const float k_r = D - 0.5f * v1;     // x[col+1]
    const float k_l = D + 0.5f * v1;     // x[col-1]
    const float k_u = D - 0.5f * v2;     // x[row-1]
    const float k_d = D + 0.5f * v2;     // x[row+1]

    // XCD-aware swizzle: hardware round-robins blockIdx.x across 8 XCDs.
    // db = (bid%8)*bpx + bid/8 gives each XCD a CONTIGUOUS chunk of data-blocks
    // (= 32 whole samples), so boundary rows are reused within one L2.
    const int bid = blockIdx.x;
    const int db  = (bid & (NXCD - 1)) * blocks_per_xcd + (bid >> 3);

    const int idx  = db * blockDim.x + threadIdx.x;   // vec4 index, exact cover
    const int vcol = idx & (VROW - 1);
    const int r    = (idx >> VROW_SHIFT) & LM;
    const int sbase_v = idx & ~((L * VROW) - 1);      // sample * 65536

    const int up_v = sbase_v + (((r - 1) & LM) << VROW_SHIFT) + vcol;
    const int dn_v = sbase_v + (((r + 1) & LM) << VROW_SHIFT) + vcol;

    const float4 ctr = x4[idx];
    const float4 up  = x4[up_v];
    const float4 dn  = x4[dn_v];

    const int    c         = vcol << 2;
    const size_t rowbase_e = ((size_t)(sbase_v + (r << VROW_SHIFT))) << 2;
    const float  le = x[rowbase_e + (size_t)((c - 1) & LM)];
    const float  re = x[rowbase_e + (size_t)((c + 4) & LM)];

    float4 o;
    o.x = k_c * ctr.x + k_r * ctr.y + k_l * le    + k_u * up.x + k_d * dn.x + bf;
    o.y = k_c * ctr.y + k_r * ctr.z + k_l * ctr.x + k_u * up.y + k_d * dn.y + bf;
    o.z = k_c * ctr.z + k_r * ctr.w + k_l * ctr.y + k_u * up.z + k_d * dn.z + bf;
    o.w = k_c * ctr.w + k_r * re    + k_l * ctr.z + k_u * up.w + k_d * dn.w + bf;
    out4[idx] = o;
}

extern "C" void kernel_launch(void* const* d_in, const int* in_sizes, int n_in,
                              void* d_out, int out_size, void* d_ws, size_t ws_size,
                              hipStream_t stream) {
    const float* x   = (const float*)d_in[0];
    const float* dp  = (const float*)d_in[1];
    const float* v1p = (const float*)d_in[2];
    const float* v2p = (const float*)d_in[3];
    const float* bfp = (const float*)d_in[4];
    float* out = (float*)d_out;

    const int total_vec = in_sizes[0] / 4;      // 16,777,216 vec4s
    const int block     = 256;
    const int grid      = total_vec / block;    // 65536 blocks, exact cover
    const int bpx       = grid / NXCD;          // 8192 blocks per XCD

    stencil5_swz_kernel<<<grid, block, 0, stream>>>(
        (const float4*)x, x, (float4*)out, dp, v1p, v2p, bfp, bpx);
}

// Round 5
// 76.459 us; speedup vs baseline: 2.1659x; 1.3467x over previous
//
#include <hip/hip_runtime.h>

#define L 512               // lattice side
#define LM (L - 1)          // 511 mask
#define VROW (L / 4)        // 128 vec4 per row
#define VROW_SHIFT 7
#define NXCD 8
#define RPT 4               // rows per thread (fully unrolled strip)

typedef float v4f __attribute__((ext_vector_type(4)));  // native vec for nontemporal store

__global__ __launch_bounds__(256) void stencil5_r4_kernel(
    const float4* __restrict__ x4,
    const float*  __restrict__ x,
    v4f* __restrict__ out4,
    const float* __restrict__ dp,
    const float* __restrict__ v1p,
    const float* __restrict__ v2p,
    const float* __restrict__ bfp,
    int blocks_per_xcd)
{
    const float d  = *dp;
    const float v1 = *v1p;
    const float v2 = *v2p;
    const float bf = *bfp;
    const float D  = d * d;
    const float k_c = 1.0f - 4.0f * D;
    const float k_r = D - 0.5f * v1;
    const float k_l = D + 0.5f * v1;
    const float k_u = D - 0.5f * v2;
    const float k_d = D + 0.5f * v2;

    // XCD-aware swizzle: each XCD gets a contiguous chunk (= 32 whole samples).
    const int bid = blockIdx.x;
    const int db  = (bid & (NXCD - 1)) * blocks_per_xcd + (bid >> 3);

    const int idx    = db * 256 + threadIdx.x;     // thread in rgroup units
    const int vcol   = idx & (VROW - 1);
    const int g      = idx >> VROW_SHIFT;          // global row-group
    const int rg     = g & (L / RPT - 1);          // 0..127 within sample
    const int sample = g >> 7;                     // 128 rgroups/sample
    const int base_v = sample << 16;               // sample * 65536 vec4s
    const int r0     = rg << 2;                    // rows r0..r0+3, no wrap inside

    const int vm = base_v + (((r0 - 1) & LM) << VROW_SHIFT) + vcol;  // row r0-1 (wraps)
    const int v0 = base_v + (r0 << VROW_SHIFT) + vcol;
    const int vp = base_v + (((r0 + 4) & LM) << VROW_SHIFT) + vcol;  // row r0+4 (wraps)

    // all 6 row loads issued up front — independent, full MLP
    const float4 rm = x4[vm];
    const float4 c0 = x4[v0];
    const float4 c1 = x4[v0 + VROW];
    const float4 c2 = x4[v0 + 2 * VROW];
    const float4 c3 = x4[v0 + 3 * VROW];
    const float4 rp = x4[vp];

    const int cl = ((vcol << 2) - 1) & LM;
    const int cr = ((vcol << 2) + 4) & LM;
    const size_t rb = ((size_t)v0 - vcol) << 2;    // element base of row r0
    const float le0 = x[rb + 0 * L + cl], re0 = x[rb + 0 * L + cr];
    const float le1 = x[rb + 1 * L + cl], re1 = x[rb + 1 * L + cr];
    const float le2 = x[rb + 2 * L + cl], re2 = x[rb + 2 * L + cr];
    const float le3 = x[rb + 3 * L + cl], re3 = x[rb + 3 * L + cr];

    v4f o;
    // row 0: up=rm dn=c1
    o.x = k_c * c0.x + k_r * c0.y + k_l * le0  + k_u * rm.x + k_d * c1.x + bf;
    o.y = k_c * c0.y + k_r * c0.z + k_l * c0.x + k_u * rm.y + k_d * c1.y + bf;
    o.z = k_c * c0.z + k_r * c0.w + k_l * c0.y + k_u * rm.z + k_d * c1.z + bf;
    o.w = k_c * c0.w + k_r * re0  + k_l * c0.z + k_u * rm.w + k_d * c1.w + bf;
    __builtin_nontemporal_store(o, &out4[v0]);
    // row 1: up=c0 dn=c2
    o.x = k_c * c1.x + k_r * c1.y + k_l * le1  + k_u * c0.x + k_d * c2.x + bf;
    o.y = k_c * c1.y + k_r * c1.z + k_l * c1.x + k_u * c0.y + k_d * c2.y + bf;
    o.z = k_c * c1.z + k_r * c1.w + k_l * c1.y + k_u * c0.z + k_d * c2.z + bf;
    o.w = k_c * c1.w + k_r * re1  + k_l * c1.z + k_u * c0.w + k_d * c2.w + bf;
    __builtin_nontemporal_store(o, &out4[v0 + VROW]);
    // row 2: up=c1 dn=c3
    o.x = k_c * c2.x + k_r * c2.y + k_l * le2  + k_u * c1.x + k_d * c3.x + bf;
    o.y = k_c * c2.y + k_r * c2.z + k_l * c2.x + k_u * c1.y + k_d * c3.y + bf;
    o.z = k_c * c2.z + k_r * c2.w + k_l * c2.y + k_u * c1.z + k_d * c3.z + bf;
    o.w = k_c * c2.w + k_r * re2  + k_l * c2.z + k_u * c1.w + k_d * c3.w + bf;
    __builtin_nontemporal_store(o, &out4[v0 + 2 * VROW]);
    // row 3: up=c2 dn=rp
    o.x = k_c * c3.x + k_r * c3.y + k_l * le3  + k_u * c2.x + k_d * rp.x + bf;
    o.y = k_c * c3.y + k_r * c3.z + k_l * c3.x + k_u * c2.y + k_d * rp.y + bf;
    o.z = k_c * c3.z + k_r * c3.w + k_l * c3.y + k_u * c2.z + k_d * rp.z + bf;
    o.w = k_c * c3.w + k_r * re3  + k_l * c3.z + k_u * c2.w + k_d * rp.w + bf;
    __builtin_nontemporal_store(o, &out4[v0 + 3 * VROW]);
}

extern "C" void kernel_launch(void* const* d_in, const int* in_sizes, int n_in,
                              void* d_out, int out_size, void* d_ws, size_t ws_size,
                              hipStream_t stream) {
    const float* x   = (const float*)d_in[0];
    const float* dp  = (const float*)d_in[1];
    const float* v1p = (const float*)d_in[2];
    const float* v2p = (const float*)d_in[3];
    const float* bfp = (const float*)d_in[4];
    float* out = (float*)d_out;

    const int total_vec = in_sizes[0] / 4;            // 16,777,216 vec4s
    const int threads   = total_vec / RPT;            // 4,194,304 threads
    const int block     = 256;
    const int grid      = threads / block;            // 16384 blocks, exact cover
    const int bpx       = grid / NXCD;                // 2048 blocks/XCD = 32 samples

    stencil5_r4_kernel<<<grid, block, 0, stream>>>(
        (const float4*)x, x, (v4f*)out, dp, v1p, v2p, bfp, bpx);
}